// Round 3
// baseline (302.718 us; speedup 1.0000x reference)
//
#include <hip/hip_runtime.h>
#include <math.h>

#define NCLS 92
#define NTGT 2048

__global__ __launch_bounds__(256) void matcher_cost_kernel(
    const float* __restrict__ logits,   // [BQ, 92]
    const float* __restrict__ pboxes,   // [BQ, 4]  cxcywh
    const int*   __restrict__ tlabels,  // [T]
    const float* __restrict__ tboxes,   // [T, 4]   cxcywh
    float* __restrict__ out)            // [BQ, T]
{
    const int row  = blockIdx.x;
    const int tid  = threadIdx.x;
    const int lane = tid & 63;

    __shared__ float s_prob[NCLS];

    // ---------- softmax over C=92 (each wave redundantly; wave 0 writes) ----------
    const float* lrow = logits + (long)row * NCLS;
    float v0 = lrow[lane];                                    // lane < 64 < 92
    float v1 = (lane + 64 < NCLS) ? lrow[lane + 64] : -INFINITY;
    float m = fmaxf(v0, v1);
    #pragma unroll
    for (int s = 32; s >= 1; s >>= 1) m = fmaxf(m, __shfl_xor(m, s, 64));
    float e0 = expf(v0 - m);
    float e1 = (lane + 64 < NCLS) ? expf(v1 - m) : 0.0f;
    float ssum = e0 + e1;
    #pragma unroll
    for (int s = 32; s >= 1; s >>= 1) ssum += __shfl_xor(ssum, s, 64);
    const float rs = 1.0f / ssum;   // once per wave, exact
    if (tid < 64) {
        s_prob[lane] = e0 * rs;
        if (lane + 64 < NCLS) s_prob[lane + 64] = e1 * rs;
    }

    // ---------- pred box -> xyxy + area (registers; broadcast load) ----------
    const float4 pb = *(const float4*)(pboxes + (long)row * 4);
    const float pcx = pb.x, pcy = pb.y, pw = pb.z, ph = pb.w;
    const float px0 = pcx - 0.5f * pw, py0 = pcy - 0.5f * ph;
    const float px1 = pcx + 0.5f * pw, py1 = pcy + 0.5f * ph;
    const float parea = (px1 - px0) * (py1 - py0);   // match reference arithmetic

    __syncthreads();

    float* orow = out + (long)row * NTGT;

    // ---------- 2048 targets: 2 passes x 4 targets/thread, float4 stores ----------
    #pragma unroll
    for (int pass = 0; pass < 2; ++pass) {
        const int t = pass * 1024 + tid * 4;
        const int4 lab = *(const int4*)(tlabels + t);
        float c[4];
        #pragma unroll
        for (int j = 0; j < 4; ++j) {
            const float4 tb = *(const float4*)(tboxes + (long)(t + j) * 4);
            const float tcx = tb.x, tcy = tb.y, tw = tb.z, th = tb.w;
            const float tx0 = tcx - 0.5f * tw, ty0 = tcy - 0.5f * th;
            const float tx1 = tcx + 0.5f * tw, ty1 = tcy + 0.5f * th;
            const float tarea = (tx1 - tx0) * (ty1 - ty0);

            const int labj = (j == 0) ? lab.x : (j == 1) ? lab.y : (j == 2) ? lab.z : lab.w;
            const float cc = -s_prob[labj];

            const float cb = fabsf(pcx - tcx) + fabsf(pcy - tcy)
                           + fabsf(pw  - tw ) + fabsf(ph  - th );

            // intersection
            const float xl = fmaxf(px0, tx0), yt = fmaxf(py0, ty0);
            const float xr = fminf(px1, tx1), yb = fminf(py1, ty1);
            const float iw = fmaxf(xr - xl, 0.0f), ih = fmaxf(yb - yt, 0.0f);
            const float inter = iw * ih;
            const float uni = parea + tarea - inter;
            const float iou = __fdividef(inter, uni);
            // enclosing box
            const float ex0 = fminf(px0, tx0), ey0 = fminf(py0, ty0);
            const float ex1 = fmaxf(px1, tx1), ey1 = fmaxf(py1, ty1);
            const float ew = fmaxf(ex1 - ex0, 0.0f), eh = fmaxf(ey1 - ey0, 0.0f);
            const float earea = ew * eh;
            const float giou = iou - __fdividef(earea - uni, earea);

            c[j] = cc + 5.0f * cb - 2.0f * giou;
        }
        *(float4*)(orow + t) = make_float4(c[0], c[1], c[2], c[3]);
    }
}

extern "C" void kernel_launch(void* const* d_in, const int* in_sizes, int n_in,
                              void* d_out, int out_size, void* d_ws, size_t ws_size,
                              hipStream_t stream) {
    const float* logits  = (const float*)d_in[0];   // [32*900, 92]
    const float* pboxes  = (const float*)d_in[1];   // [32*900, 4]
    const int*   tlabels = (const int*)  d_in[2];   // [2048]
    const float* tboxes  = (const float*)d_in[3];   // [2048, 4]
    float* out = (float*)d_out;                     // [32*900, 2048]

    const int BQ = in_sizes[1] / 4;                 // 28800 rows
    matcher_cost_kernel<<<BQ, 256, 0, stream>>>(logits, pboxes, tlabels, tboxes, out);
}

// Round 5
// 298.603 us; speedup vs baseline: 1.0138x; 1.0138x over previous
//
#include <hip/hip_runtime.h>
#include <math.h>

#define NCLS 92
#define NTGT 2048
#define ROWS 16     // rows (b,q) per block

typedef float vfloat4 __attribute__((ext_vector_type(4)));

__global__ __launch_bounds__(256) void matcher_cost_kernel(
    const float* __restrict__ logits,   // [BQ, 92]
    const float* __restrict__ pboxes,   // [BQ, 4]  cxcywh
    const int*   __restrict__ tlabels,  // [T]
    const float* __restrict__ tboxes,   // [T, 4]   cxcywh
    float* __restrict__ out,            // [BQ, T]
    int BQ)
{
    const int row0 = blockIdx.x * ROWS;
    const int tid  = threadIdx.x;
    const int rlim = min(ROWS, BQ - row0);

    __shared__ float s_prob[ROWS][NCLS + 1];  // stride 93 words (odd -> spreads banks)
    __shared__ float s_pb[ROWS][12];          // px0,py0,px1,py1 | parea,pcx,pcy,pw | ph,-,-,-

    // ---- 16 softmaxes in parallel: 16-lane group g handles row g ----
    {
        const int g = tid >> 4;
        const int l = tid & 15;
        const int gr = (g < rlim) ? g : 0;               // clamp for OOB rows
        const float* lrow = logits + (long)(row0 + gr) * NCLS;
        float v[6];
        float m = -INFINITY;
        #pragma unroll
        for (int k = 0; k < 6; ++k) {
            const int c = l + k * 16;
            v[k] = (c < NCLS) ? lrow[c] : -INFINITY;
            m = fmaxf(m, v[k]);
        }
        #pragma unroll
        for (int s = 8; s >= 1; s >>= 1) m = fmaxf(m, __shfl_xor(m, s, 16));
        float sum = 0.0f;
        #pragma unroll
        for (int k = 0; k < 6; ++k) {
            const int c = l + k * 16;
            v[k] = (c < NCLS) ? expf(v[k] - m) : 0.0f;
            sum += v[k];
        }
        #pragma unroll
        for (int s = 8; s >= 1; s >>= 1) sum += __shfl_xor(sum, s, 16);
        const float rs = 1.0f / sum;
        #pragma unroll
        for (int k = 0; k < 6; ++k) {
            const int c = l + k * 16;
            if (c < NCLS) s_prob[g][c] = v[k] * rs;
        }
    }
    // ---- pred boxes -> xyxy + area, staged in LDS ----
    if (tid < ROWS) {
        const int r = (tid < rlim) ? tid : 0;
        const float4 pb = *(const float4*)(pboxes + (long)(row0 + r) * 4);
        const float px0 = pb.x - 0.5f * pb.z, py0 = pb.y - 0.5f * pb.w;
        const float px1 = pb.x + 0.5f * pb.z, py1 = pb.y + 0.5f * pb.w;
        *(float4*)&s_pb[tid][0] = make_float4(px0, py0, px1, py1);
        *(float4*)&s_pb[tid][4] = make_float4((px1 - px0) * (py1 - py0), pb.x, pb.y, pb.z);
        s_pb[tid][8] = pb.w;
    }
    __syncthreads();

    float* oblk = out + (long)row0 * NTGT;

    // ---- 2 passes x 4 targets/thread; targets converted ONCE, reused over 16 rows ----
    #pragma unroll
    for (int pass = 0; pass < 2; ++pass) {
        const int t = pass * 1024 + tid * 4;
        const int4 lab = *(const int4*)(tlabels + t);
        const int labs[4] = {lab.x, lab.y, lab.z, lab.w};

        float tx0[4], ty0[4], tx1[4], ty1[4], tarea[4], tcx[4], tcy[4], tw[4], th[4];
        #pragma unroll
        for (int j = 0; j < 4; ++j) {
            const float4 tb = *(const float4*)(tboxes + (long)(t + j) * 4);
            tcx[j] = tb.x; tcy[j] = tb.y; tw[j] = tb.z; th[j] = tb.w;
            tx0[j] = tb.x - 0.5f * tb.z; ty0[j] = tb.y - 0.5f * tb.w;
            tx1[j] = tb.x + 0.5f * tb.z; ty1[j] = tb.y + 0.5f * tb.w;
            tarea[j] = (tx1[j] - tx0[j]) * (ty1[j] - ty0[j]);
        }

        #pragma unroll 2
        for (int r = 0; r < ROWS; ++r) {
            if (r >= rlim) break;
            const float4 p0 = *(const float4*)&s_pb[r][0];   // px0 py0 px1 py1 (broadcast)
            const float4 p1 = *(const float4*)&s_pb[r][4];   // parea pcx pcy pw
            const float  ph = s_pb[r][8];
            float c[4];
            #pragma unroll
            for (int j = 0; j < 4; ++j) {
                const float cc = -s_prob[r][labs[j]];

                const float cb = fabsf(p1.y - tcx[j]) + fabsf(p1.z - tcy[j])
                               + fabsf(p1.w - tw[j]) + fabsf(ph - th[j]);

                const float xl = fmaxf(p0.x, tx0[j]), yt = fmaxf(p0.y, ty0[j]);
                const float xr = fminf(p0.z, tx1[j]), yb = fminf(p0.w, ty1[j]);
                const float iw = fmaxf(xr - xl, 0.0f), ih = fmaxf(yb - yt, 0.0f);
                const float inter = iw * ih;
                const float uni = p1.x + tarea[j] - inter;
                const float iou = __fdividef(inter, uni);

                const float ex0 = fminf(p0.x, tx0[j]), ey0 = fminf(p0.y, ty0[j]);
                const float ex1 = fmaxf(p0.z, tx1[j]), ey1 = fmaxf(p0.w, ty1[j]);
                const float ew = fmaxf(ex1 - ex0, 0.0f), eh = fmaxf(ey1 - ey0, 0.0f);
                const float earea = ew * eh;
                const float giou = iou - __fdividef(earea - uni, earea);

                c[j] = cc + 5.0f * cb - 2.0f * giou;
            }
            vfloat4 cv;
            cv.x = c[0]; cv.y = c[1]; cv.z = c[2]; cv.w = c[3];
            __builtin_nontemporal_store(cv, (vfloat4*)(oblk + (long)r * NTGT + t));
        }
    }
}

extern "C" void kernel_launch(void* const* d_in, const int* in_sizes, int n_in,
                              void* d_out, int out_size, void* d_ws, size_t ws_size,
                              hipStream_t stream) {
    const float* logits  = (const float*)d_in[0];   // [28800, 92]
    const float* pboxes  = (const float*)d_in[1];   // [28800, 4]
    const int*   tlabels = (const int*)  d_in[2];   // [2048]
    const float* tboxes  = (const float*)d_in[3];   // [2048, 4]
    float* out = (float*)d_out;                     // [28800, 2048]

    const int BQ = in_sizes[1] / 4;                 // 28800 rows
    const int nblk = (BQ + ROWS - 1) / ROWS;        // 1800
    matcher_cost_kernel<<<nblk, 256, 0, stream>>>(logits, pboxes, tlabels, tboxes, out, BQ);
}

// Round 6
// 269.806 us; speedup vs baseline: 1.1220x; 1.1067x over previous
//
#include <hip/hip_runtime.h>
#include <math.h>

#define NCLS 92
#define NTGT 2048
#define ROWS 16     // rows (b,q) per block

typedef float vfloat4 __attribute__((ext_vector_type(4)));

// Guaranteed fast division: v_rcp_f32 + v_mul_f32 (avoid IEEE div_scale/div_fmas/div_fixup seq)
__device__ __forceinline__ float fast_div(float a, float b) {
    return a * __builtin_amdgcn_rcpf(b);
}

__global__ __launch_bounds__(256) void matcher_cost_kernel(
    const float* __restrict__ logits,   // [BQ, 92]
    const float* __restrict__ pboxes,   // [BQ, 4]  cxcywh
    const int*   __restrict__ tlabels,  // [T]
    const float* __restrict__ tboxes,   // [T, 4]   cxcywh
    float* __restrict__ out,            // [BQ, T]
    int BQ)
{
    const int row0 = blockIdx.x * ROWS;
    const int tid  = threadIdx.x;
    const int rlim = min(ROWS, BQ - row0);

    __shared__ float s_prob[ROWS][NCLS + 1];  // stride 93 words
    __shared__ float s_pb[ROWS][12];          // px0,py0,px1,py1 | parea,pcx,pcy,pw | ph

    // ---- 16 softmaxes in parallel: 16-lane group g handles row g ----
    {
        const int g = tid >> 4;
        const int l = tid & 15;
        const int gr = (g < rlim) ? g : 0;
        const float* lrow = logits + (long)(row0 + gr) * NCLS;
        float v[6];
        float m = -INFINITY;
        #pragma unroll
        for (int k = 0; k < 6; ++k) {
            const int c = l + k * 16;
            v[k] = (c < NCLS) ? lrow[c] : -INFINITY;
            m = fmaxf(m, v[k]);
        }
        #pragma unroll
        for (int s = 8; s >= 1; s >>= 1) m = fmaxf(m, __shfl_xor(m, s, 16));
        float sum = 0.0f;
        #pragma unroll
        for (int k = 0; k < 6; ++k) {
            const int c = l + k * 16;
            v[k] = (c < NCLS) ? expf(v[k] - m) : 0.0f;
            sum += v[k];
        }
        #pragma unroll
        for (int s = 8; s >= 1; s >>= 1) sum += __shfl_xor(sum, s, 16);
        const float rs = 1.0f / sum;   // once per row, exact
        #pragma unroll
        for (int k = 0; k < 6; ++k) {
            const int c = l + k * 16;
            if (c < NCLS) s_prob[g][c] = v[k] * rs;
        }
    }
    // ---- pred boxes -> xyxy + area, staged in LDS ----
    if (tid < ROWS) {
        const int r = (tid < rlim) ? tid : 0;
        const float4 pb = *(const float4*)(pboxes + (long)(row0 + r) * 4);
        const float px0 = pb.x - 0.5f * pb.z, py0 = pb.y - 0.5f * pb.w;
        const float px1 = pb.x + 0.5f * pb.z, py1 = pb.y + 0.5f * pb.w;
        *(float4*)&s_pb[tid][0] = make_float4(px0, py0, px1, py1);
        *(float4*)&s_pb[tid][4] = make_float4((px1 - px0) * (py1 - py0), pb.x, pb.y, pb.z);
        s_pb[tid][8] = pb.w;
    }
    __syncthreads();

    float* oblk = out + (long)row0 * NTGT;

    #pragma unroll
    for (int pass = 0; pass < 2; ++pass) {
        const int t = pass * 1024 + tid * 4;
        const int4 lab = *(const int4*)(tlabels + t);
        const int labs[4] = {lab.x, lab.y, lab.z, lab.w};

        float tx0[4], ty0[4], tx1[4], ty1[4], tarea[4], tcx[4], tcy[4], tw[4], th[4];
        #pragma unroll
        for (int j = 0; j < 4; ++j) {
            const float4 tb = *(const float4*)(tboxes + (long)(t + j) * 4);
            tcx[j] = tb.x; tcy[j] = tb.y; tw[j] = tb.z; th[j] = tb.w;
            tx0[j] = tb.x - 0.5f * tb.z; ty0[j] = tb.y - 0.5f * tb.w;
            tx1[j] = tb.x + 0.5f * tb.z; ty1[j] = tb.y + 0.5f * tb.w;
            tarea[j] = (tx1[j] - tx0[j]) * (ty1[j] - ty0[j]);
        }

        auto body = [&](int r) {
            const float4 p0 = *(const float4*)&s_pb[r][0];   // px0 py0 px1 py1 (broadcast)
            const float4 p1 = *(const float4*)&s_pb[r][4];   // parea pcx pcy pw
            const float  ph = s_pb[r][8];
            float c[4];
            #pragma unroll
            for (int j = 0; j < 4; ++j) {
                const float cc = -s_prob[r][labs[j]];

                const float cb = fabsf(p1.y - tcx[j]) + fabsf(p1.z - tcy[j])
                               + fabsf(p1.w - tw[j]) + fabsf(ph - th[j]);

                const float xl = fmaxf(p0.x, tx0[j]), yt = fmaxf(p0.y, ty0[j]);
                const float xr = fminf(p0.z, tx1[j]), yb = fminf(p0.w, ty1[j]);
                const float iw = fmaxf(xr - xl, 0.0f), ih = fmaxf(yb - yt, 0.0f);
                const float inter = iw * ih;
                const float uni = p1.x + tarea[j] - inter;
                const float iou = fast_div(inter, uni);

                const float ex0 = fminf(p0.x, tx0[j]), ey0 = fminf(p0.y, ty0[j]);
                const float ex1 = fmaxf(p0.z, tx1[j]), ey1 = fmaxf(p0.w, ty1[j]);
                const float ew = fmaxf(ex1 - ex0, 0.0f), eh = fmaxf(ey1 - ey0, 0.0f);
                const float earea = ew * eh;
                const float giou = iou - fast_div(earea - uni, earea);

                c[j] = cc + 5.0f * cb - 2.0f * giou;
            }
            vfloat4 cv;
            cv.x = c[0]; cv.y = c[1]; cv.z = c[2]; cv.w = c[3];
            __builtin_nontemporal_store(cv, (vfloat4*)(oblk + (long)r * NTGT + t));
        };

        if (rlim == ROWS) {
            #pragma unroll 4
            for (int r = 0; r < ROWS; ++r) body(r);   // clean path: no per-iter branch
        } else {
            for (int r = 0; r < rlim; ++r) body(r);
        }
    }
}

extern "C" void kernel_launch(void* const* d_in, const int* in_sizes, int n_in,
                              void* d_out, int out_size, void* d_ws, size_t ws_size,
                              hipStream_t stream) {
    const float* logits  = (const float*)d_in[0];   // [28800, 92]
    const float* pboxes  = (const float*)d_in[1];   // [28800, 4]
    const int*   tlabels = (const int*)  d_in[2];   // [2048]
    const float* tboxes  = (const float*)d_in[3];   // [2048, 4]
    float* out = (float*)d_out;                     // [28800, 2048]

    const int BQ = in_sizes[1] / 4;                 // 28800 rows
    const int nblk = (BQ + ROWS - 1) / ROWS;        // 1800
    matcher_cost_kernel<<<nblk, 256, 0, stream>>>(logits, pboxes, tlabels, tboxes, out, BQ);
}